// Round 1
// baseline (1643.405 us; speedup 1.0000x reference)
//
#include <hip/hip_runtime.h>
#include <hip/hip_bf16.h>
#include <stdint.h>

#define TOKENS 4096
#define DMODEL 1024
#define VOCAB  50257
#define KSEL   64
#define NSPLIT 8
#define MTILES (TOKENS / 64)                       // 64
#define COLS_PER ((VOCAB + NSPLIT - 1) / NSPLIT)   // 6283
#define CAP 128
#define MERGE_THR 65

typedef unsigned short u16;
typedef __attribute__((ext_vector_type(8))) short bf16x8;
typedef __attribute__((ext_vector_type(4))) float f32x4;

__device__ __forceinline__ u16 f2bf(float f) {
  uint32_t u = __float_as_uint(f);
  u = (u + 0x7fffu + ((u >> 16) & 1u)) >> 16;   // RNE
  return (u16)u;
}

// ---------------------------------------------------------------------------
// Kernel 1: convert x,b -> bf16 and compute fp32 squared norms.
// One block per row (1024 floats = 256 threads x float4).
// ---------------------------------------------------------------------------
__global__ __launch_bounds__(256) void prep_kernel(
    const float* __restrict__ x, const float* __restrict__ b,
    u16* __restrict__ xh, u16* __restrict__ bh,
    float* __restrict__ xsq, float* __restrict__ bsq) {
  int row = blockIdx.x;
  int tid = threadIdx.x;
  const float* src;
  u16* dst;
  float* nrm;
  int r;
  if (row < TOKENS) {
    r = row; src = x + (size_t)r * DMODEL; dst = xh + (size_t)r * DMODEL; nrm = xsq;
  } else {
    r = row - TOKENS; src = b + (size_t)r * DMODEL; dst = bh + (size_t)r * DMODEL; nrm = bsq;
  }
  float4 v = reinterpret_cast<const float4*>(src)[tid];
  float s = v.x * v.x + v.y * v.y + v.z * v.z + v.w * v.w;
  ushort4 h;
  h.x = f2bf(v.x); h.y = f2bf(v.y); h.z = f2bf(v.z); h.w = f2bf(v.w);
  reinterpret_cast<ushort4*>(dst)[tid] = h;
#pragma unroll
  for (int j = 1; j < 64; j <<= 1) s += __shfl_xor(s, j);
  __shared__ float acc4[4];
  if ((tid & 63) == 0) acc4[tid >> 6] = s;
  __syncthreads();
  if (tid == 0) nrm[r] = acc4[0] + acc4[1] + acc4[2] + acc4[3];
}

// ---------------------------------------------------------------------------
// Kernel 2: fused bf16 MFMA GEMM (dist = xsq + bsq - 2 x.b) + streaming top-64.
// Block: 64 query rows x one vocab split. 4 waves, 64x64 output chunks.
// ---------------------------------------------------------------------------
__global__ __launch_bounds__(256, 2) void gemm_topk_kernel(
    const u16* __restrict__ xh, const u16* __restrict__ bh,
    const float* __restrict__ xsq, const float* __restrict__ bsq,
    float* __restrict__ parts) {
  __shared__ u16 As[64][72];       // +8 pad: conflict-free staging & ~2-way frag reads
  __shared__ u16 Bs[64][72];
  __shared__ float list[64][KSEL]; // per-row sorted (asc) current top-64
  __shared__ float cbuf[64][CAP];  // per-row candidate buffer
  __shared__ float tau[64];        // list[r][63]
  __shared__ int   ccnt[64];
  __shared__ float xsq_s[64];

  const int tid  = threadIdx.x;
  const int lane = tid & 63;
  const int wave = tid >> 6;
  const int bid  = blockIdx.x;
  const int mt   = bid & (MTILES - 1);   // consecutive bids share XCD-residue -> A-tiles L2-resident
  const int ns   = bid >> 6;

  const int mrow0 = mt * 64;
  const int col0  = ns * COLS_PER;
  const int col1  = (col0 + COLS_PER < VOCAB) ? (col0 + COLS_PER) : VOCAB;
  const int nchunk = (col1 - col0 + 63) >> 6;

  if (tid < 64) {
    tau[tid] = __builtin_inff();
    ccnt[tid] = 0;
    xsq_s[tid] = xsq[mrow0 + tid];
  }
  for (int i = tid; i < 64 * KSEL; i += 256) (&list[0][0])[i] = __builtin_inff();
  __syncthreads();

  const int wm = wave >> 1, wn = wave & 1;
  const int row_w = wm * 32, col_w = wn * 32;
  const int fr = lane & 15;          // frag m (A) / n (B)
  const int kf = (lane >> 4) * 8;    // frag k offset
  const int rj = (lane >> 4) * 4;    // C/D row base
  const int srow = tid >> 3;         // staging row 0..31
  const int skc  = (tid & 7) * 8;    // staging k col

  for (int ch = 0; ch < nchunk; ++ch) {
    const int cbase = col0 + (ch << 6);
    f32x4 acc[2][2];
#pragma unroll
    for (int i = 0; i < 2; ++i)
#pragma unroll
      for (int j = 0; j < 2; ++j) acc[i][j] = (f32x4){0.f, 0.f, 0.f, 0.f};

    for (int ks = 0; ks < DMODEL; ks += 64) {
      __syncthreads();
#pragma unroll
      for (int i = 0; i < 2; ++i) {
        int rr = i * 32 + srow;
        const u16* ga = xh + (size_t)(mrow0 + rr) * DMODEL + ks + skc;
        *reinterpret_cast<int4*>(&As[rr][skc]) = *reinterpret_cast<const int4*>(ga);
        int gc = cbase + rr; if (gc > VOCAB - 1) gc = VOCAB - 1;   // clamp, masked later
        const u16* gb = bh + (size_t)gc * DMODEL + ks + skc;
        *reinterpret_cast<int4*>(&Bs[rr][skc]) = *reinterpret_cast<const int4*>(gb);
      }
      __syncthreads();
#pragma unroll
      for (int kk = 0; kk < 64; kk += 32) {
        bf16x8 a0 = *reinterpret_cast<const bf16x8*>(&As[row_w + fr][kk + kf]);
        bf16x8 a1 = *reinterpret_cast<const bf16x8*>(&As[row_w + 16 + fr][kk + kf]);
        bf16x8 b0 = *reinterpret_cast<const bf16x8*>(&Bs[col_w + fr][kk + kf]);
        bf16x8 b1 = *reinterpret_cast<const bf16x8*>(&Bs[col_w + 16 + fr][kk + kf]);
        acc[0][0] = __builtin_amdgcn_mfma_f32_16x16x32_bf16(a0, b0, acc[0][0], 0, 0, 0);
        acc[0][1] = __builtin_amdgcn_mfma_f32_16x16x32_bf16(a0, b1, acc[0][1], 0, 0, 0);
        acc[1][0] = __builtin_amdgcn_mfma_f32_16x16x32_bf16(a1, b0, acc[1][0], 0, 0, 0);
        acc[1][1] = __builtin_amdgcn_mfma_f32_16x16x32_bf16(a1, b1, acc[1][1], 0, 0, 0);
      }
    }

    // ---- push candidates (dist < tau) into per-row buffers ----
#pragma unroll
    for (int fm = 0; fm < 2; ++fm) {
#pragma unroll
      for (int fn = 0; fn < 2; ++fn) {
        int c = cbase + col_w + fn * 16 + fr;
        bool cv = (c < col1);
        float bq = cv ? bsq[c] : 0.f;
#pragma unroll
        for (int j = 0; j < 4; ++j) {
          int rl = row_w + fm * 16 + rj + j;
          float dist = xsq_s[rl] + bq - 2.0f * acc[fm][fn][j];
          if (cv && dist < tau[rl]) {
            int ix = atomicAdd(&ccnt[rl], 1);
            if (ix < CAP) cbuf[rl][ix] = dist;   // policy guarantees ix < 128
          }
        }
      }
    }
    __syncthreads();

    // ---- merge phase: wave w owns rows w, w+4, ... ----
    const bool lastch = (ch == nchunk - 1);
#pragma unroll 1
    for (int r = wave; r < 64; r += 4) {
      int cnt = ccnt[r];
      if (cnt >= MERGE_THR || (lastch && cnt > 0)) {
        float v0 = (lane < cnt) ? cbuf[r][lane] : __builtin_inff();
        float v1 = (lane + 64 < cnt) ? cbuf[r][lane + 64] : __builtin_inff();
        // in-register bitonic sort of 128 (virtual idx: v0->lane, v1->64+lane)
#pragma unroll
        for (int k = 2; k <= 128; k <<= 1) {
#pragma unroll
          for (int j = k >> 1; j > 0; j >>= 1) {
            if (j == 64) {
              float lo = fminf(v0, v1), hi = fmaxf(v0, v1);
              v0 = lo; v1 = hi;                     // k=128: ascending
            } else {
              {
                float p = __shfl_xor(v0, j);
                bool keepmin = (((lane & j) == 0) == ((lane & k) == 0));
                v0 = keepmin ? fminf(v0, p) : fmaxf(v0, p);
              }
              {
                float p = __shfl_xor(v1, j);
                bool keepmin = (((lane & j) == 0) == (((64 | lane) & k) == 0));
                v1 = keepmin ? fminf(v1, p) : fmaxf(v1, p);
              }
            }
          }
        }
        // bitonic top-k merge: list (asc) vs candidates' 64 smallest (reversed)
        float rev = __shfl(v0, 63 - lane);
        float m = fminf(list[r][lane], rev);
#pragma unroll
        for (int j = 32; j > 0; j >>= 1) {
          float p = __shfl_xor(m, j);
          m = ((lane & j) == 0) ? fminf(m, p) : fmaxf(m, p);
        }
        list[r][lane] = m;
        if (lane == 63) { tau[r] = m; ccnt[r] = 0; }
      }
    }
    __syncthreads();
  }

  // write split-partial top-64 (sorted asc)
  for (int i = tid; i < 64 * KSEL; i += 256) {
    int r = i >> 6, l = i & 63;
    parts[(size_t)(mrow0 + r) * (NSPLIT * KSEL) + ns * KSEL + l] = list[r][l];
  }
}

// ---------------------------------------------------------------------------
// Kernel 3: merge the 8 split-partials per row: sort 512, emit 64 smallest asc.
// ---------------------------------------------------------------------------
__global__ __launch_bounds__(256) void final_merge_kernel(
    const float* __restrict__ parts, float* __restrict__ out) {
  int row = blockIdx.x;
  int tid = threadIdx.x;
  __shared__ float s[NSPLIT * KSEL];   // 512
  s[tid]       = parts[(size_t)row * (NSPLIT * KSEL) + tid];
  s[tid + 256] = parts[(size_t)row * (NSPLIT * KSEL) + tid + 256];
  __syncthreads();
  for (int k = 2; k <= 512; k <<= 1) {
    for (int j = k >> 1; j > 0; j >>= 1) {
      int i = ((tid & ~(j - 1)) << 1) | (tid & (j - 1));
      int p = i | j;
      bool asc = ((i & k) == 0);
      float a = s[i], bb = s[p];
      bool sw = asc ? (a > bb) : (a < bb);
      if (sw) { s[i] = bb; s[p] = a; }
      __syncthreads();
    }
  }
  if (tid < KSEL) out[(size_t)row * KSEL + tid] = s[tid];
}

// ---------------------------------------------------------------------------
extern "C" void kernel_launch(void* const* d_in, const int* in_sizes, int n_in,
                              void* d_out, int out_size, void* d_ws, size_t ws_size,
                              hipStream_t stream) {
  const float* x = (const float*)d_in[0];
  const float* b = (const float*)d_in[1];
  // d_in[2] = target (unused by reference forward), d_in[3] = k (hardcoded 64)
  float* out = (float*)d_out;
  char* ws = (char*)d_ws;

  size_t off = 0;
  u16* xh = (u16*)(ws + off); off += (size_t)TOKENS * DMODEL * sizeof(u16);   // 8 MB
  u16* bh = (u16*)(ws + off); off += (size_t)VOCAB * DMODEL * sizeof(u16);    // ~103 MB
  float* xsq = (float*)(ws + off); off += (size_t)TOKENS * sizeof(float);
  float* bsq = (float*)(ws + off); off += (((size_t)VOCAB * sizeof(float)) + 255) & ~(size_t)255;
  float* parts = (float*)(ws + off); off += (size_t)TOKENS * NSPLIT * KSEL * sizeof(float); // 8 MB
  // total ~120 MB of ws

  prep_kernel<<<TOKENS + VOCAB, 256, 0, stream>>>(x, b, xh, bh, xsq, bsq);
  gemm_topk_kernel<<<MTILES * NSPLIT, 256, 0, stream>>>(xh, bh, xsq, bsq, parts);
  final_merge_kernel<<<TOKENS, 256, 0, stream>>>(parts, out);
}

// Round 2
// 1433.785 us; speedup vs baseline: 1.1462x; 1.1462x over previous
//
#include <hip/hip_runtime.h>
#include <hip/hip_bf16.h>
#include <stdint.h>

#define TOKENS 4096
#define DMODEL 1024
#define VOCAB  50257
#define KSEL   64
#define NSPLIT 16
#define BM 128
#define BN 128
#define BK 64
#define MTILES (TOKENS / BM)                       // 32
#define COLS_PER ((VOCAB + NSPLIT - 1) / NSPLIT)   // 3142
#define CAP 80
#define MERGE_THR 17
#define INF __builtin_inff()

typedef unsigned short u16;
typedef __attribute__((ext_vector_type(8))) short bf16x8;
typedef __attribute__((ext_vector_type(4))) float f32x4;

// global -> LDS direct copy, 16B/lane. LDS dest is wave-uniform base + lane*16.
#define GLOAD16(gp, lp) __builtin_amdgcn_global_load_lds( \
    (const __attribute__((address_space(1))) void*)(gp),  \
    (__attribute__((address_space(3))) void*)(lp), 16, 0, 0)

__device__ __forceinline__ u16 f2bf(float f) {
  uint32_t u = __float_as_uint(f);
  u = (u + 0x7fffu + ((u >> 16) & 1u)) >> 16;   // RNE
  return (u16)u;
}

// ---------------------------------------------------------------------------
// Kernel 1: x,b -> bf16 + fp32 squared norms. One block per row.
// ---------------------------------------------------------------------------
__global__ __launch_bounds__(256) void prep_kernel(
    const float* __restrict__ x, const float* __restrict__ b,
    u16* __restrict__ xh, u16* __restrict__ bh,
    float* __restrict__ xsq, float* __restrict__ bsq) {
  int row = blockIdx.x;
  int tid = threadIdx.x;
  const float* src;
  u16* dst;
  float* nrm;
  int r;
  if (row < TOKENS) {
    r = row; src = x + (size_t)r * DMODEL; dst = xh + (size_t)r * DMODEL; nrm = xsq;
  } else {
    r = row - TOKENS; src = b + (size_t)r * DMODEL; dst = bh + (size_t)r * DMODEL; nrm = bsq;
  }
  float4 v = reinterpret_cast<const float4*>(src)[tid];
  float s = v.x * v.x + v.y * v.y + v.z * v.z + v.w * v.w;
  ushort4 h;
  h.x = f2bf(v.x); h.y = f2bf(v.y); h.z = f2bf(v.z); h.w = f2bf(v.w);
  reinterpret_cast<ushort4*>(dst)[tid] = h;
#pragma unroll
  for (int j = 1; j < 64; j <<= 1) s += __shfl_xor(s, j);
  __shared__ float acc4[4];
  if ((tid & 63) == 0) acc4[tid >> 6] = s;
  __syncthreads();
  if (tid == 0) nrm[r] = acc4[0] + acc4[1] + acc4[2] + acc4[3];
}

// ---------------------------------------------------------------------------
// merge_row: sort candidate buffer (<=CAP, lane-held), merge 64 smallest into
// sorted list value lstv (asc). One code copy (noinline) — 32 call sites.
// ---------------------------------------------------------------------------
__device__ __attribute__((noinline)) float merge_row(float lstv, const float* cb, int cnt) {
  const int lane = threadIdx.x & 63;
  float v0 = (lane < cnt) ? cb[lane] : INF;
  if (cnt > 64) {
    float v1 = (lane + 64 < cnt) ? cb[lane + 64] : INF;
    // full bitonic sort of 128 (virtual idx: v0->lane, v1->64+lane), asc
#pragma unroll
    for (int k = 2; k <= 128; k <<= 1) {
#pragma unroll
      for (int j = k >> 1; j > 0; j >>= 1) {
        if (j == 64) {
          float lo = fminf(v0, v1), hi = fmaxf(v0, v1);
          v0 = lo; v1 = hi;
        } else {
          {
            float p = __shfl_xor(v0, j);
            bool keepmin = (((lane & j) == 0) == ((lane & k) == 0));
            v0 = keepmin ? fminf(v0, p) : fmaxf(v0, p);
          }
          {
            float p = __shfl_xor(v1, j);
            bool keepmin = (((lane & j) == 0) == (((64 | lane) & k) == 0));
            v1 = keepmin ? fminf(v1, p) : fmaxf(v1, p);
          }
        }
      }
    }
  } else {
    // fast path: sort-64 asc (common case)
#pragma unroll
    for (int k = 2; k <= 64; k <<= 1) {
#pragma unroll
      for (int j = k >> 1; j > 0; j >>= 1) {
        float p = __shfl_xor(v0, j);
        bool keepmin = (((lane & j) == 0) == ((lane & k) == 0));
        v0 = keepmin ? fminf(v0, p) : fmaxf(v0, p);
      }
    }
  }
  // bitonic top-64 merge: lstv (asc across lanes) vs v0 reversed
  float rev = __shfl(v0, 63 - lane);
  float m = fminf(lstv, rev);
#pragma unroll
  for (int j = 32; j > 0; j >>= 1) {
    float p = __shfl_xor(m, j);
    m = ((lane & j) == 0) ? fminf(m, p) : fmaxf(m, p);
  }
  return m;
}

// ---------------------------------------------------------------------------
// Kernel 2: m97-structure bf16 MFMA GEMM (128x128 tile, BK=64, 8 waves,
// global_load_lds width=16) fused with streaming top-64.
// Wave (wm,wn): computes rows wm*32..+32 x cols wn*64..+64; merges rows
// wm*32+wn*16..+16 (sorted lists live in registers, 16/lane).
// ---------------------------------------------------------------------------
__global__ __launch_bounds__(512, 4) void gemm_topk_kernel(
    const u16* __restrict__ xh, const u16* __restrict__ bh,
    const float* __restrict__ xsq, const float* __restrict__ bsq,
    float* __restrict__ parts) {
  __shared__ u16 As[BM * BK];        // linear [128][64], 16KB (global_load_lds dest)
  __shared__ u16 Bs[BN * BK];        // 16KB
  __shared__ float cbuf[BM][CAP];    // 40KB candidate buffers
  __shared__ float tau[BM];
  __shared__ int   ccnt[BM];
  __shared__ float xsq_s[BM];
  // total ~73.5KB -> 2 blocks/CU

  const int tid  = threadIdx.x;
  const int lane = tid & 63;
  const int wave = tid >> 6;            // 0..7
  const int bid  = blockIdx.x;
  const int mt   = bid & (MTILES - 1);
  const int ns   = bid >> 5;

  const int mrow0 = mt * BM;
  const int col0  = ns * COLS_PER;
  const int col1  = (col0 + COLS_PER < VOCAB) ? (col0 + COLS_PER) : VOCAB;
  const int nchunk = (col1 - col0 + BN - 1) / BN;

  if (tid < BM) {
    tau[tid] = INF;
    ccnt[tid] = 0;
    xsq_s[tid] = xsq[mrow0 + tid];
  }
  __syncthreads();

  float lst[16];                        // this wave's 16 rows' sorted top-64
#pragma unroll
  for (int i = 0; i < 16; ++i) lst[i] = INF;

  const int wm = wave >> 1, wn = wave & 1;
  const int fr = lane & 15;             // frag row (A) / col (B)
  const int kf = (lane >> 4) * 8;       // frag k element offset
  const int rj = (lane >> 4) * 4;       // C/D row base within frag
  const int r0 = wm * 32 + wn * 16;     // merge-owned rows base

  // staging geometry: 16 segs of 1KB per tile; wave stages segs {wave, wave+8}
  const int srow_in_seg = lane >> 3;    // 0..7
  const int scol = (lane & 7) * 8;      // element col (16B per lane)

#pragma unroll 1
  for (int ch = 0; ch < nchunk; ++ch) {
    const int cbase = col0 + ch * BN;
    f32x4 acc[2][4];
#pragma unroll
    for (int i = 0; i < 2; ++i)
#pragma unroll
      for (int j = 0; j < 4; ++j) acc[i][j] = (f32x4){0.f, 0.f, 0.f, 0.f};

#pragma unroll 1
    for (int ks = 0; ks < DMODEL; ks += BK) {
      __syncthreads();                  // prev K-step's reads done before overwrite
#pragma unroll
      for (int sg = 0; sg < 2; ++sg) {
        const int seg = wave + sg * 8;            // 0..15 (wave-uniform)
        const int row = seg * 8 + srow_in_seg;    // 0..127
        const u16* ga = xh + (size_t)(mrow0 + row) * DMODEL + ks + scol;
        GLOAD16(ga, &As[seg * 512]);
        int gc = cbase + row; if (gc > VOCAB - 1) gc = VOCAB - 1;  // clamp, masked later
        const u16* gb = bh + (size_t)gc * DMODEL + ks + scol;
        GLOAD16(gb, &Bs[seg * 512]);
      }
      __syncthreads();                  // drains vmcnt(0): tiles ready
#pragma unroll
      for (int kk = 0; kk < BK; kk += 32) {
        bf16x8 a0 = *reinterpret_cast<const bf16x8*>(&As[(wm * 32 + fr) * BK + kk + kf]);
        bf16x8 a1 = *reinterpret_cast<const bf16x8*>(&As[(wm * 32 + 16 + fr) * BK + kk + kf]);
        bf16x8 b0 = *reinterpret_cast<const bf16x8*>(&Bs[(wn * 64 + fr) * BK + kk + kf]);
        bf16x8 b1 = *reinterpret_cast<const bf16x8*>(&Bs[(wn * 64 + 16 + fr) * BK + kk + kf]);
        bf16x8 b2 = *reinterpret_cast<const bf16x8*>(&Bs[(wn * 64 + 32 + fr) * BK + kk + kf]);
        bf16x8 b3 = *reinterpret_cast<const bf16x8*>(&Bs[(wn * 64 + 48 + fr) * BK + kk + kf]);
        acc[0][0] = __builtin_amdgcn_mfma_f32_16x16x32_bf16(a0, b0, acc[0][0], 0, 0, 0);
        acc[0][1] = __builtin_amdgcn_mfma_f32_16x16x32_bf16(a0, b1, acc[0][1], 0, 0, 0);
        acc[0][2] = __builtin_amdgcn_mfma_f32_16x16x32_bf16(a0, b2, acc[0][2], 0, 0, 0);
        acc[0][3] = __builtin_amdgcn_mfma_f32_16x16x32_bf16(a0, b3, acc[0][3], 0, 0, 0);
        acc[1][0] = __builtin_amdgcn_mfma_f32_16x16x32_bf16(a1, b0, acc[1][0], 0, 0, 0);
        acc[1][1] = __builtin_amdgcn_mfma_f32_16x16x32_bf16(a1, b1, acc[1][1], 0, 0, 0);
        acc[1][2] = __builtin_amdgcn_mfma_f32_16x16x32_bf16(a1, b2, acc[1][2], 0, 0, 0);
        acc[1][3] = __builtin_amdgcn_mfma_f32_16x16x32_bf16(a1, b3, acc[1][3], 0, 0, 0);
      }
    }

    // ---- filter + merge, two 64-col halves (caps cbuf growth at 64/half) ----
#pragma unroll
    for (int h = 0; h < 2; ++h) {
#pragma unroll
      for (int fm = 0; fm < 2; ++fm) {
#pragma unroll
        for (int fn2 = 0; fn2 < 2; ++fn2) {
          const int fn = h * 2 + fn2;
          const int c = cbase + wn * 64 + fn * 16 + fr;
          const bool cv = (c < col1);
          const float bq = cv ? bsq[c] : 0.f;
#pragma unroll
          for (int j = 0; j < 4; ++j) {
            const int rl = wm * 32 + fm * 16 + rj + j;
            const float dist = xsq_s[rl] + bq - 2.0f * acc[fm][fn][j];
            if (cv && dist < tau[rl]) {
              int ix = atomicAdd(&ccnt[rl], 1);
              if (ix < CAP) cbuf[rl][ix] = dist;   // policy guarantees ix < CAP
            }
          }
        }
      }
      __syncthreads();
      const bool last = (ch == nchunk - 1) && (h == 1);
#pragma unroll
      for (int rl16 = 0; rl16 < 16; ++rl16) {      // static idx into lst (rule #20)
        const int r = r0 + rl16;
        const int cnt = ccnt[r];
        if (cnt >= MERGE_THR || (last && cnt > 0)) {
          float m = merge_row(lst[rl16], &cbuf[r][0], cnt);
          lst[rl16] = m;
          if (lane == 63) { tau[r] = m; ccnt[r] = 0; }
        }
      }
      __syncthreads();
    }
  }

  // write split-partial top-64 (sorted asc) from registers
#pragma unroll
  for (int rl16 = 0; rl16 < 16; ++rl16) {
    parts[(size_t)(mrow0 + r0 + rl16) * (NSPLIT * KSEL) + ns * KSEL + lane] = lst[rl16];
  }
}

// ---------------------------------------------------------------------------
// Kernel 3: per row, tree-merge 16 sorted 64-lists down to the 64 smallest.
// One wave per row, all in registers.
// ---------------------------------------------------------------------------
__device__ __forceinline__ float merge64(float a, float b, int lane) {
  // both sorted asc across lanes; returns sorted asc 64 smallest of union
  float rev = __shfl(b, 63 - lane);
  float m = fminf(a, rev);
#pragma unroll
  for (int j = 32; j > 0; j >>= 1) {
    float p = __shfl_xor(m, j);
    m = ((lane & j) == 0) ? fminf(m, p) : fmaxf(m, p);
  }
  return m;
}

__global__ __launch_bounds__(256) void final_merge_kernel(
    const float* __restrict__ parts, float* __restrict__ out) {
  const int lane = threadIdx.x & 63;
  const int row = blockIdx.x * 4 + (threadIdx.x >> 6);
  float v[16];
#pragma unroll
  for (int i = 0; i < 16; ++i)
    v[i] = parts[(size_t)row * (NSPLIT * KSEL) + i * KSEL + lane];
#pragma unroll
  for (int i = 0; i < 8; ++i) v[i] = merge64(v[i], v[i + 8], lane);
#pragma unroll
  for (int i = 0; i < 4; ++i) v[i] = merge64(v[i], v[i + 4], lane);
#pragma unroll
  for (int i = 0; i < 2; ++i) v[i] = merge64(v[i], v[i + 2], lane);
  v[0] = merge64(v[0], v[1], lane);
  out[(size_t)row * KSEL + lane] = v[0];
}

// ---------------------------------------------------------------------------
extern "C" void kernel_launch(void* const* d_in, const int* in_sizes, int n_in,
                              void* d_out, int out_size, void* d_ws, size_t ws_size,
                              hipStream_t stream) {
  const float* x = (const float*)d_in[0];
  const float* b = (const float*)d_in[1];
  // d_in[2] = target (unused), d_in[3] = k (hardcoded 64)
  float* out = (float*)d_out;
  char* ws = (char*)d_ws;

  size_t off = 0;
  u16* xh = (u16*)(ws + off); off += (size_t)TOKENS * DMODEL * sizeof(u16);   // 8.4 MB
  u16* bh = (u16*)(ws + off); off += (size_t)VOCAB * DMODEL * sizeof(u16);    // 103 MB
  float* xsq = (float*)(ws + off); off += (size_t)TOKENS * sizeof(float);
  float* bsq = (float*)(ws + off); off += (((size_t)VOCAB * sizeof(float)) + 255) & ~(size_t)255;
  float* parts = (float*)(ws + off); off += (size_t)TOKENS * NSPLIT * KSEL * sizeof(float); // 16.8 MB

  prep_kernel<<<TOKENS + VOCAB, 256, 0, stream>>>(x, b, xh, bh, xsq, bsq);
  gemm_topk_kernel<<<MTILES * NSPLIT, 512, 0, stream>>>(xh, bh, xsq, bsq, parts);
  final_merge_kernel<<<TOKENS / 4, 256, 0, stream>>>(parts, out);
}

// Round 3
// 1164.577 us; speedup vs baseline: 1.4112x; 1.2312x over previous
//
#include <hip/hip_runtime.h>
#include <hip/hip_bf16.h>
#include <stdint.h>

#define TOKENS 4096
#define DMODEL 1024
#define VOCAB  50257
#define KSEL   64
#define NSPLIT 16
#define BM 128
#define BN 128
#define BK 64
#define MTILES (TOKENS / BM)                       // 32
#define COLS_PER ((VOCAB + NSPLIT - 1) / NSPLIT)   // 3142
#define CAP 80
#define MERGE_THR 17
#define INF __builtin_inff()

typedef unsigned short u16;
typedef __attribute__((ext_vector_type(8))) short bf16x8;
typedef __attribute__((ext_vector_type(4))) float f32x4;

// global -> LDS direct copy, 16B/lane. LDS dest is wave-uniform base + lane*16.
#define GLOAD16(gp, lp) __builtin_amdgcn_global_load_lds( \
    (const __attribute__((address_space(1))) void*)(gp),  \
    (__attribute__((address_space(3))) void*)(lp), 16, 0, 0)

__device__ __forceinline__ u16 f2bf(float f) {
  uint32_t u = __float_as_uint(f);
  u = (u + 0x7fffu + ((u >> 16) & 1u)) >> 16;   // RNE
  return (u16)u;
}

// swizzled LDS element offset for logical (row, kElem); kElem multiple of 8.
// 16B-slot XOR by (row&7): lanes 0..15 (rows r..r+15, same k-slot) spread
// across all 8 bank-quads x2 => 2-way = conflict-free (m136).
__device__ __forceinline__ int swz(int row, int ke) {
  return row * BK + ((((ke) >> 3) ^ (row & 7)) << 3);
}

// ---------------------------------------------------------------------------
// Kernel 1: x,b -> bf16 + fp32 squared norms. One block per row.
// ---------------------------------------------------------------------------
__global__ __launch_bounds__(256) void prep_kernel(
    const float* __restrict__ x, const float* __restrict__ b,
    u16* __restrict__ xh, u16* __restrict__ bh,
    float* __restrict__ xsq, float* __restrict__ bsq) {
  int row = blockIdx.x;
  int tid = threadIdx.x;
  const float* src;
  u16* dst;
  float* nrm;
  int r;
  if (row < TOKENS) {
    r = row; src = x + (size_t)r * DMODEL; dst = xh + (size_t)r * DMODEL; nrm = xsq;
  } else {
    r = row - TOKENS; src = b + (size_t)r * DMODEL; dst = bh + (size_t)r * DMODEL; nrm = bsq;
  }
  float4 v = reinterpret_cast<const float4*>(src)[tid];
  float s = v.x * v.x + v.y * v.y + v.z * v.z + v.w * v.w;
  ushort4 h;
  h.x = f2bf(v.x); h.y = f2bf(v.y); h.z = f2bf(v.z); h.w = f2bf(v.w);
  reinterpret_cast<ushort4*>(dst)[tid] = h;
#pragma unroll
  for (int j = 1; j < 64; j <<= 1) s += __shfl_xor(s, j);
  __shared__ float acc4[4];
  if ((tid & 63) == 0) acc4[tid >> 6] = s;
  __syncthreads();
  if (tid == 0) nrm[r] = acc4[0] + acc4[1] + acc4[2] + acc4[3];
}

// ---------------------------------------------------------------------------
// merge_row: sort candidate buffer (<=CAP, lane-held), merge 64 smallest into
// sorted list value lstv (asc). One code copy (noinline).
// ---------------------------------------------------------------------------
__device__ __attribute__((noinline)) float merge_row(float lstv, const float* cb, int cnt) {
  const int lane = threadIdx.x & 63;
  float v0 = (lane < cnt) ? cb[lane] : INF;
  if (cnt > 64) {
    float v1 = (lane + 64 < cnt) ? cb[lane + 64] : INF;
    // full bitonic sort of 128 (virtual idx: v0->lane, v1->64+lane), asc
#pragma unroll
    for (int k = 2; k <= 128; k <<= 1) {
#pragma unroll
      for (int j = k >> 1; j > 0; j >>= 1) {
        if (j == 64) {
          float lo = fminf(v0, v1), hi = fmaxf(v0, v1);
          v0 = lo; v1 = hi;
        } else {
          {
            float p = __shfl_xor(v0, j);
            bool keepmin = (((lane & j) == 0) == ((lane & k) == 0));
            v0 = keepmin ? fminf(v0, p) : fmaxf(v0, p);
          }
          {
            float p = __shfl_xor(v1, j);
            bool keepmin = (((lane & j) == 0) == (((64 | lane) & k) == 0));
            v1 = keepmin ? fminf(v1, p) : fmaxf(v1, p);
          }
        }
      }
    }
  } else {
    // fast path: sort-64 asc (common case)
#pragma unroll
    for (int k = 2; k <= 64; k <<= 1) {
#pragma unroll
      for (int j = k >> 1; j > 0; j >>= 1) {
        float p = __shfl_xor(v0, j);
        bool keepmin = (((lane & j) == 0) == ((lane & k) == 0));
        v0 = keepmin ? fminf(v0, p) : fmaxf(v0, p);
      }
    }
  }
  // bitonic top-64 merge: lstv (asc across lanes) vs v0 reversed
  float rev = __shfl(v0, 63 - lane);
  float m = fminf(lstv, rev);
#pragma unroll
  for (int j = 32; j > 0; j >>= 1) {
    float p = __shfl_xor(m, j);
    m = ((lane & j) == 0) ? fminf(m, p) : fmaxf(m, p);
  }
  return m;
}

// ---------------------------------------------------------------------------
// Kernel 2: 128x128 bf16 MFMA GEMM (BK=64, 8 waves, global_load_lds w=16,
// both-sides LDS swizzle) fused with streaming top-64.
// ---------------------------------------------------------------------------
__global__ __launch_bounds__(512, 4) void gemm_topk_kernel(
    const u16* __restrict__ xh, const u16* __restrict__ bh,
    const float* __restrict__ xsq, const float* __restrict__ bsq,
    float* __restrict__ parts) {
  __shared__ u16 As[BM * BK];        // linear [128][64] elems, swizzled slots, 16KB
  __shared__ u16 Bs[BN * BK];        // 16KB
  __shared__ float cbuf[BM][CAP];    // 40KB candidate buffers
  __shared__ float tau[BM];
  __shared__ int   ccnt[BM];
  __shared__ float xsq_s[BM];
  // total ~73.5KB -> 2 blocks/CU (16 waves/CU)

  const int tid  = threadIdx.x;
  const int lane = tid & 63;
  const int wave = tid >> 6;            // 0..7
  // bijective XCD swizzle (512 blocks = 64/XCD): each XCD owns 2 vocab splits
  const int bid  = (blockIdx.x & 7) * 64 + (blockIdx.x >> 3);
  const int mt   = bid & (MTILES - 1);
  const int ns   = bid >> 5;

  const int mrow0 = mt * BM;
  const int col0  = ns * COLS_PER;
  const int col1  = (col0 + COLS_PER < VOCAB) ? (col0 + COLS_PER) : VOCAB;
  const int nchunk = (col1 - col0 + BN - 1) / BN;

  // staging geometry: 16 segs of 1KB per tile; wave stages segs {wave, wave+8}.
  // source slot pre-swizzled so linear LDS dest holds swizzled layout (rule #21)
  const int srow = lane >> 3;                 // row within seg 0..7 (== row&7)
  const int scol = ((lane & 7) ^ srow) * 8;   // pre-swizzled 16B slot -> elem col

#define STAGE(ks_, cbase_) do {                                              \
    _Pragma("unroll")                                                        \
    for (int sg = 0; sg < 2; ++sg) {                                         \
      const int seg = wave + sg * 8;                                         \
      const int row = seg * 8 + srow;                                        \
      const u16* ga = xh + (size_t)(mrow0 + row) * DMODEL + (ks_) + scol;    \
      GLOAD16(ga, &As[seg * 512]);                                           \
      int gc = (cbase_) + row; if (gc > VOCAB - 1) gc = VOCAB - 1;           \
      const u16* gb = bh + (size_t)gc * DMODEL + (ks_) + scol;               \
      GLOAD16(gb, &Bs[seg * 512]);                                           \
    }                                                                        \
  } while (0)

  STAGE(0, col0);                       // prologue: first chunk's first K-step

  if (tid < BM) {
    tau[tid] = INF;
    ccnt[tid] = 0;
    xsq_s[tid] = xsq[mrow0 + tid];
  }

  float lst[16];                        // this wave's 16 rows' sorted top-64
#pragma unroll
  for (int i = 0; i < 16; ++i) lst[i] = INF;

  const int wm = wave >> 1, wn = wave & 1;
  const int fr = lane & 15;             // frag row (A) / col (B)
  const int kf = (lane >> 4) * 8;       // frag k element offset
  const int rj = (lane >> 4) * 4;       // C/D row base within frag
  const int r0 = wm * 32 + wn * 16;     // merge-owned rows base

#pragma unroll 1
  for (int ch = 0; ch < nchunk; ++ch) {
    const int cbase = col0 + ch * BN;
    f32x4 acc[2][4];
#pragma unroll
    for (int i = 0; i < 2; ++i)
#pragma unroll
      for (int j = 0; j < 4; ++j) acc[i][j] = (f32x4){0.f, 0.f, 0.f, 0.f};

#pragma unroll 1
    for (int ks = 0; ks < DMODEL; ks += BK) {
      if (ks) {
        __syncthreads();                // prev K-step reads done before overwrite
        STAGE(ks, cbase);
      }
      __syncthreads();                  // drains vmcnt(0): tiles ready
#pragma unroll
      for (int kk = 0; kk < BK; kk += 32) {
        bf16x8 a0 = *reinterpret_cast<const bf16x8*>(&As[swz(wm * 32 + fr,      kk + kf)]);
        bf16x8 a1 = *reinterpret_cast<const bf16x8*>(&As[swz(wm * 32 + 16 + fr, kk + kf)]);
        bf16x8 b0 = *reinterpret_cast<const bf16x8*>(&Bs[swz(wn * 64 + fr,      kk + kf)]);
        bf16x8 b1 = *reinterpret_cast<const bf16x8*>(&Bs[swz(wn * 64 + 16 + fr, kk + kf)]);
        bf16x8 b2 = *reinterpret_cast<const bf16x8*>(&Bs[swz(wn * 64 + 32 + fr, kk + kf)]);
        bf16x8 b3 = *reinterpret_cast<const bf16x8*>(&Bs[swz(wn * 64 + 48 + fr, kk + kf)]);
        acc[0][0] = __builtin_amdgcn_mfma_f32_16x16x32_bf16(a0, b0, acc[0][0], 0, 0, 0);
        acc[0][1] = __builtin_amdgcn_mfma_f32_16x16x32_bf16(a0, b1, acc[0][1], 0, 0, 0);
        acc[0][2] = __builtin_amdgcn_mfma_f32_16x16x32_bf16(a0, b2, acc[0][2], 0, 0, 0);
        acc[0][3] = __builtin_amdgcn_mfma_f32_16x16x32_bf16(a0, b3, acc[0][3], 0, 0, 0);
        acc[1][0] = __builtin_amdgcn_mfma_f32_16x16x32_bf16(a1, b0, acc[1][0], 0, 0, 0);
        acc[1][1] = __builtin_amdgcn_mfma_f32_16x16x32_bf16(a1, b1, acc[1][1], 0, 0, 0);
        acc[1][2] = __builtin_amdgcn_mfma_f32_16x16x32_bf16(a1, b2, acc[1][2], 0, 0, 0);
        acc[1][3] = __builtin_amdgcn_mfma_f32_16x16x32_bf16(a1, b3, acc[1][3], 0, 0, 0);
      }
    }

    __syncthreads();                    // ALL waves done reading tiles
    if (ch + 1 < nchunk) STAGE(0, cbase + BN);   // issue-early: hides under pushes

    // ---- filter + merge, two 64-col halves (caps cbuf growth at 64/half) ----
#pragma unroll
    for (int h = 0; h < 2; ++h) {
#pragma unroll
      for (int fm = 0; fm < 2; ++fm) {
#pragma unroll
        for (int fn2 = 0; fn2 < 2; ++fn2) {
          const int fn = h * 2 + fn2;
          const int c = cbase + wn * 64 + fn * 16 + fr;
          const bool cv = (c < col1);
          const float bq = cv ? bsq[c] : 0.f;
#pragma unroll
          for (int j = 0; j < 4; ++j) {
            const int rl = wm * 32 + fm * 16 + rj + j;
            const float dist = xsq_s[rl] + bq - 2.0f * acc[fm][fn][j];
            if (cv && dist < tau[rl]) {
              int ix = atomicAdd(&ccnt[rl], 1);
              if (ix < CAP) cbuf[rl][ix] = dist;   // policy guarantees ix < CAP
            }
          }
        }
      }
      __syncthreads();
      const bool last = (ch == nchunk - 1) && (h == 1);
#pragma unroll
      for (int rl16 = 0; rl16 < 16; ++rl16) {      // static idx into lst (rule #20)
        const int r = r0 + rl16;
        const int cnt = ccnt[r];
        if (cnt >= MERGE_THR || (last && cnt > 0)) {
          float m = merge_row(lst[rl16], &cbuf[r][0], cnt);
          lst[rl16] = m;
          if (lane == 63) { tau[r] = m; ccnt[r] = 0; }
        }
      }
      if (h == 0) __syncthreads();      // h=1's visibility covered by next drain-sync
    }
  }

  // write split-partial top-64 (sorted asc) from registers
#pragma unroll
  for (int rl16 = 0; rl16 < 16; ++rl16) {
    parts[(size_t)(mrow0 + r0 + rl16) * (NSPLIT * KSEL) + ns * KSEL + lane] = lst[rl16];
  }
#undef STAGE
}

// ---------------------------------------------------------------------------
// Kernel 3: per row, tree-merge 16 sorted 64-lists down to the 64 smallest.
// ---------------------------------------------------------------------------
__device__ __forceinline__ float merge64(float a, float b, int lane) {
  float rev = __shfl(b, 63 - lane);
  float m = fminf(a, rev);
#pragma unroll
  for (int j = 32; j > 0; j >>= 1) {
    float p = __shfl_xor(m, j);
    m = ((lane & j) == 0) ? fminf(m, p) : fmaxf(m, p);
  }
  return m;
}

__global__ __launch_bounds__(256) void final_merge_kernel(
    const float* __restrict__ parts, float* __restrict__ out) {
  const int lane = threadIdx.x & 63;
  const int row = blockIdx.x * 4 + (threadIdx.x >> 6);
  float v[16];
#pragma unroll
  for (int i = 0; i < 16; ++i)
    v[i] = parts[(size_t)row * (NSPLIT * KSEL) + i * KSEL + lane];
#pragma unroll
  for (int i = 0; i < 8; ++i) v[i] = merge64(v[i], v[i + 8], lane);
#pragma unroll
  for (int i = 0; i < 4; ++i) v[i] = merge64(v[i], v[i + 4], lane);
#pragma unroll
  for (int i = 0; i < 2; ++i) v[i] = merge64(v[i], v[i + 2], lane);
  v[0] = merge64(v[0], v[1], lane);
  out[(size_t)row * KSEL + lane] = v[0];
}

// ---------------------------------------------------------------------------
extern "C" void kernel_launch(void* const* d_in, const int* in_sizes, int n_in,
                              void* d_out, int out_size, void* d_ws, size_t ws_size,
                              hipStream_t stream) {
  const float* x = (const float*)d_in[0];
  const float* b = (const float*)d_in[1];
  // d_in[2] = target (unused), d_in[3] = k (hardcoded 64)
  float* out = (float*)d_out;
  char* ws = (char*)d_ws;

  size_t off = 0;
  u16* xh = (u16*)(ws + off); off += (size_t)TOKENS * DMODEL * sizeof(u16);   // 8.4 MB
  u16* bh = (u16*)(ws + off); off += (size_t)VOCAB * DMODEL * sizeof(u16);    // 103 MB
  float* xsq = (float*)(ws + off); off += (size_t)TOKENS * sizeof(float);
  float* bsq = (float*)(ws + off); off += (((size_t)VOCAB * sizeof(float)) + 255) & ~(size_t)255;
  float* parts = (float*)(ws + off); off += (size_t)TOKENS * NSPLIT * KSEL * sizeof(float); // 16.8 MB

  prep_kernel<<<TOKENS + VOCAB, 256, 0, stream>>>(x, b, xh, bh, xsq, bsq);
  gemm_topk_kernel<<<MTILES * NSPLIT, 512, 0, stream>>>(xh, bh, xsq, bsq, parts);
  final_merge_kernel<<<TOKENS / 4, 256, 0, stream>>>(parts, out);
}